// Round 5
// baseline (225.229 us; speedup 1.0000x reference)
//
#include <hip/hip_runtime.h>
#include <hip/hip_bf16.h>

// Problem constants (from reference): B=8, C=16, H=512, W=512, M=15, N=15
#define BC    128          // B*C
#define Hh    512
#define Ww    512
#define P16   16           // M+1
#define Q16   16           // N+1
#define HTILE 64           // h rows per eval block
#define NHT   (Hh / HTILE) // 8 h-tiles

// ---------------------------------------------------------------------------
// Kernel 1: extract separable factors from the provided basis input.
// basis[n, p, q] = Bu[h,p] * Bv[w,q] with n = h*W + w; Bernstein rows sum to 1.
//   Bu[h,p] = sum_q basis[h*W + 0, p, q]      (sum of 16 contiguous floats)
//   Bv[w,q] = sum_p basis[0*W + w, p, q]      (stride-16 float column)
// One thread per output element: 8192 (h,p) + 8192 (w,q) = 64 blocks x 256.
// ---------------------------------------------------------------------------
__global__ __launch_bounds__(256)
void extract_factors(const float* __restrict__ basis,
                     float* __restrict__ Bu,
                     float* __restrict__ Bv) {
    int tid = blockIdx.x * 256 + threadIdx.x;      // 0..16383
    if (tid < Hh * P16) {
        int h = tid >> 4, p = tid & 15;
        const float4* row = (const float4*)(basis + (size_t)h * Ww * (P16 * Q16) + p * Q16);
        float4 a = row[0], b = row[1], c = row[2], d = row[3];   // 64 B coalesced
        float s = ((a.x + a.y) + (a.z + a.w)) + ((b.x + b.y) + (b.z + b.w))
                + ((c.x + c.y) + (c.z + c.w)) + ((d.x + d.y) + (d.z + d.w));
        Bu[tid] = s;
    } else {
        int t2 = tid - Hh * P16;
        int w = t2 >> 4, q = t2 & 15;
        const float* col = basis + (size_t)w * (P16 * Q16) + q;
        float s = 0.f;
        #pragma unroll
        for (int p = 0; p < P16; ++p) s += col[p * Q16];
        Bv[t2] = s;
    }
}

// ---------------------------------------------------------------------------
// Kernel 2: out[bc, h, w] = sum_p Bu[h,p] * ( sum_q K[bc,p,q] * Bv[w,q] )
// Block: one bc (blockIdx.y) x one 64-row h-tile (blockIdx.x), all 512 w.
// Phase A: T[p][w] = sum_q K[p,q]*Bv[w,q] into LDS (16x512 floats).
// Phase B: T column slice in 16 NAMED float4 regs; regular float4 stores
//          (output fits in 256 MiB L3 -> dirty lines overwritten across
//           replays, HBM write traffic collapses; nt-store defeated this).
// ---------------------------------------------------------------------------
__global__ __launch_bounds__(256, 4)
void bezier_eval(const float* __restrict__ K,
                 const float* __restrict__ Bu,
                 const float* __restrict__ Bv,
                 float* __restrict__ out) {
    __shared__ float Ts[P16][Ww];        // 32 KiB
    __shared__ float Bu_s[HTILE * P16];  // 4 KiB
    __shared__ float K_s[P16 * Q16];     // 1 KiB

    const int t     = threadIdx.x;       // 0..255
    const int htile = blockIdx.x;        // 0..7
    const int bc    = blockIdx.y;        // 0..127

    // --- loads: K panel (1 float/thread), Bu tile (float4/thread) ---
    K_s[t] = K[(size_t)bc * (P16 * Q16) + t];
    *(float4*)&Bu_s[t * 4] = *(const float4*)&Bu[htile * (HTILE * P16) + t * 4];
    __syncthreads();

    // --- Phase A: T[p][w] for w = 2t, 2t+1 ---
    {
        const int w0 = t * 2;
        const float* bvp = Bv + (size_t)w0 * Q16;   // two consecutive rows, 128 B
        float bv0[Q16], bv1[Q16];
        #pragma unroll
        for (int q = 0; q < Q16; ++q) { bv0[q] = bvp[q]; bv1[q] = bvp[Q16 + q]; }
        #pragma unroll
        for (int p = 0; p < P16; ++p) {
            float s0 = 0.f, s1 = 0.f;
            #pragma unroll
            for (int q = 0; q < Q16; ++q) {
                float k = K_s[p * Q16 + q];          // wave-uniform broadcast
                s0 = fmaf(k, bv0[q], s0);
                s1 = fmaf(k, bv1[q], s1);
            }
            *(float2*)&Ts[p][w0] = make_float2(s0, s1);  // ds_write_b64, contiguous
        }
    }
    __syncthreads();

    // --- Phase B: thread -> (w0 = (t&127)*4, h rows hhalf*32 .. +31) ---
    const int w0    = (t & 127) * 4;
    const int hhalf = t >> 7;            // 0 or 1

    // 16 NAMED float4 registers — no array, no runtime indexing, no scratch.
    float4 T0  = *(const float4*)&Ts[ 0][w0];
    float4 T1  = *(const float4*)&Ts[ 1][w0];
    float4 T2  = *(const float4*)&Ts[ 2][w0];
    float4 T3  = *(const float4*)&Ts[ 3][w0];
    float4 T4  = *(const float4*)&Ts[ 4][w0];
    float4 T5  = *(const float4*)&Ts[ 5][w0];
    float4 T6  = *(const float4*)&Ts[ 6][w0];
    float4 T7  = *(const float4*)&Ts[ 7][w0];
    float4 T8  = *(const float4*)&Ts[ 8][w0];
    float4 T9  = *(const float4*)&Ts[ 9][w0];
    float4 T10 = *(const float4*)&Ts[10][w0];
    float4 T11 = *(const float4*)&Ts[11][w0];
    float4 T12 = *(const float4*)&Ts[12][w0];
    float4 T13 = *(const float4*)&Ts[13][w0];
    float4 T14 = *(const float4*)&Ts[14][w0];
    float4 T15 = *(const float4*)&Ts[15][w0];

    const size_t out_row0 = ((size_t)bc * Hh + (size_t)htile * HTILE + hhalf * 32) * Ww + w0;

    #pragma unroll 8
    for (int h = 0; h < 32; ++h) {
        const int hh = hhalf * 32 + h;
        const float4* burow = (const float4*)&Bu_s[hh * P16];  // uniform broadcast
        float4 b0 = burow[0], b1 = burow[1], b2 = burow[2], b3 = burow[3];
        float4 acc = make_float4(0.f, 0.f, 0.f, 0.f);
        #define FMA4(b, Tv) \
            acc.x = fmaf((b), (Tv).x, acc.x); \
            acc.y = fmaf((b), (Tv).y, acc.y); \
            acc.z = fmaf((b), (Tv).z, acc.z); \
            acc.w = fmaf((b), (Tv).w, acc.w);
        FMA4(b0.x, T0);  FMA4(b0.y, T1);  FMA4(b0.z, T2);  FMA4(b0.w, T3);
        FMA4(b1.x, T4);  FMA4(b1.y, T5);  FMA4(b1.z, T6);  FMA4(b1.w, T7);
        FMA4(b2.x, T8);  FMA4(b2.y, T9);  FMA4(b2.z, T10); FMA4(b2.w, T11);
        FMA4(b3.x, T12); FMA4(b3.y, T13); FMA4(b3.z, T14); FMA4(b3.w, T15);
        #undef FMA4
        *(float4*)&out[out_row0 + (size_t)h * Ww] = acc;   // regular store -> L3
    }
}

extern "C" void kernel_launch(void* const* d_in, const int* in_sizes, int n_in,
                              void* d_out, int out_size, void* d_ws, size_t ws_size,
                              hipStream_t stream) {
    const float* K     = (const float*)d_in[0];   // [128, 16, 16]
    const float* basis = (const float*)d_in[1];   // [262144, 16, 16]
    float* out = (float*)d_out;                   // [128, 512, 512]

    float* Bu = (float*)d_ws;                     // [512][16]  (32 KiB)
    float* Bv = Bu + Hh * P16;                    // [512][16]  (32 KiB)

    extract_factors<<<64, 256, 0, stream>>>(basis, Bu, Bv);

    dim3 grid(NHT, BC);
    bezier_eval<<<grid, 256, 0, stream>>>(K, Bu, Bv, out);
}

// Round 6
// 39.916 us; speedup vs baseline: 5.6425x; 5.6425x over previous
//
#include <hip/hip_runtime.h>
#include <hip/hip_bf16.h>

// Problem constants (from reference): B=8, C=16, H=512, W=512, M=15, N=15
#define BC    128          // B*C
#define Hh    512
#define Ww    512
#define P16   16           // M+1
#define Q16   16           // N+1
#define HTILE 32           // h rows per eval block
#define NHT   (Hh / HTILE) // 16 h-tiles

typedef float f32x2 __attribute__((ext_vector_type(2)));

// ---------------------------------------------------------------------------
// Kernel 1: extract separable factors from the provided basis input.
// basis[n, p, q] = Bu[h,p] * Bv[w,q] with n = h*W + w; Bernstein rows sum to 1.
//   Bu[h,p] = sum_q basis[h*W + 0, p, q]      (16 contiguous floats)
//   Bv[w,q] = sum_p basis[0*W + w, p, q]      (stride-16 column)
// ---------------------------------------------------------------------------
__global__ __launch_bounds__(256)
void extract_factors(const float* __restrict__ basis,
                     float* __restrict__ Bu,
                     float* __restrict__ Bv) {
    int tid = blockIdx.x * 256 + threadIdx.x;      // 0..16383
    if (tid < Hh * P16) {
        int h = tid >> 4, p = tid & 15;
        const float4* row = (const float4*)(basis + (size_t)h * Ww * (P16 * Q16) + p * Q16);
        float4 a = row[0], b = row[1], c = row[2], d = row[3];   // 64 B
        float s = ((a.x + a.y) + (a.z + a.w)) + ((b.x + b.y) + (b.z + b.w))
                + ((c.x + c.y) + (c.z + c.w)) + ((d.x + d.y) + (d.z + d.w));
        Bu[tid] = s;
    } else {
        int t2 = tid - Hh * P16;
        int w = t2 >> 4, q = t2 & 15;
        const float* col = basis + (size_t)w * (P16 * Q16) + q;
        float s = 0.f;
        #pragma unroll
        for (int p = 0; p < P16; ++p) s += col[p * Q16];
        Bv[t2] = s;
    }
}

// ---------------------------------------------------------------------------
// Kernel 2 (fully register-resident, zero LDS, zero barriers):
//   thread t owns w-pair w0 = 2t (x lane of float2) and w0+1 (y lane),
//   and ALL 32 h rows of its block's tile.
//   Phase A: T[p] = sum_q K[bc,p,q] * Bv[w,q]  -> 16 x float2 = 32 VGPRs.
//   Phase B: for each h: out = sum_p Bu[h,p] * T[p]; Bu/K addresses are
//   block-uniform -> scalar loads. Nontemporal stores (keep output stream
//   out of L2 so it can't evict anything).
// ---------------------------------------------------------------------------
__global__ __launch_bounds__(256, 2)
void bezier_eval(const float* __restrict__ K,
                 const float* __restrict__ Bu,
                 const float* __restrict__ Bv,
                 float* __restrict__ out) {
    const int t     = threadIdx.x;       // 0..255
    const int htile = blockIdx.x;        // 0..15
    const int bc    = blockIdx.y;        // 0..127

    const float* __restrict__ Kp = K + (size_t)bc * (P16 * Q16);  // uniform

    // ---- Phase A: build T[p] = (T[p][2t], T[p][2t+1]) ----
    float2 T[P16];
    #pragma unroll
    for (int p = 0; p < P16; ++p) T[p] = make_float2(0.f, 0.f);

    // Bv rows 2t (128B-aligned per thread) and 2t+1
    const float4* bvv = (const float4*)(Bv + (size_t)(2 * t) * Q16);

    #pragma unroll
    for (int qb = 0; qb < 2; ++qb) {               // q in blocks of 8: bv live = 16 regs
        float4 r00 = bvv[qb * 2 + 0], r01 = bvv[qb * 2 + 1];       // row 2t
        float4 r10 = bvv[4 + qb * 2 + 0], r11 = bvv[4 + qb * 2 + 1]; // row 2t+1
        #pragma unroll
        for (int p = 0; p < P16; ++p) {
            const float* kq = Kp + p * Q16 + qb * 8;   // uniform -> scalar loads
            float2 s = T[p];
            s.x = fmaf(kq[0], r00.x, s.x);  s.y = fmaf(kq[0], r10.x, s.y);
            s.x = fmaf(kq[1], r00.y, s.x);  s.y = fmaf(kq[1], r10.y, s.y);
            s.x = fmaf(kq[2], r00.z, s.x);  s.y = fmaf(kq[2], r10.z, s.y);
            s.x = fmaf(kq[3], r00.w, s.x);  s.y = fmaf(kq[3], r10.w, s.y);
            s.x = fmaf(kq[4], r01.x, s.x);  s.y = fmaf(kq[4], r11.x, s.y);
            s.x = fmaf(kq[5], r01.y, s.x);  s.y = fmaf(kq[5], r11.y, s.y);
            s.x = fmaf(kq[6], r01.z, s.x);  s.y = fmaf(kq[6], r11.z, s.y);
            s.x = fmaf(kq[7], r01.w, s.x);  s.y = fmaf(kq[7], r11.w, s.y);
            T[p] = s;
        }
    }

    // ---- Phase B: 32 output rows, Bu row is block-uniform ----
    const float* __restrict__ bu = Bu + (size_t)htile * (HTILE * P16);
    float* __restrict__ op =
        out + ((size_t)bc * Hh + (size_t)htile * HTILE) * Ww + 2 * t;

    #pragma unroll 4
    for (int h = 0; h < HTILE; ++h) {
        const float* br = bu + h * P16;            // uniform -> scalar loads
        float ax = 0.f, ay = 0.f;
        #pragma unroll
        for (int p = 0; p < P16; ++p) {
            float b = br[p];
            ax = fmaf(b, T[p].x, ax);
            ay = fmaf(b, T[p].y, ay);
        }
        f32x2 v = { ax, ay };
        __builtin_nontemporal_store(v, (f32x2*)(op + (size_t)h * Ww));
    }
}

extern "C" void kernel_launch(void* const* d_in, const int* in_sizes, int n_in,
                              void* d_out, int out_size, void* d_ws, size_t ws_size,
                              hipStream_t stream) {
    const float* K     = (const float*)d_in[0];   // [128, 16, 16]
    const float* basis = (const float*)d_in[1];   // [262144, 16, 16]
    float* out = (float*)d_out;                   // [128, 512, 512]

    float* Bu = (float*)d_ws;                     // [512][16]  (32 KiB)
    float* Bv = Bu + Hh * P16;                    // [512][16]  (32 KiB)

    extract_factors<<<64, 256, 0, stream>>>(basis, Bu, Bv);

    dim3 grid(NHT, BC);                           // 2048 blocks
    bezier_eval<<<grid, 256, 0, stream>>>(K, Bu, Bv, out);
}

// Round 7
// 39.485 us; speedup vs baseline: 5.7041x; 1.0109x over previous
//
#include <hip/hip_runtime.h>
#include <hip/hip_bf16.h>

// Problem constants (from reference): B=8, C=16, H=512, W=512, M=15, N=15
#define BC    128          // B*C
#define Hh    512
#define Ww    512
#define P16   16           // M+1
#define Q16   16           // N+1
#define HTILE 32           // h rows per eval block
#define NHT   (Hh / HTILE) // 16 h-tiles

// ---------------------------------------------------------------------------
// Kernel 1: extract separable factors from the provided basis input.
// basis[n, p, q] = Bu[h,p] * Bv[w,q] with n = h*W + w; Bernstein rows sum to 1.
//   Bu[h,p] = sum_q basis[h*W + 0, p, q]      (16 contiguous floats)
//   Bv[w,q] = sum_p basis[0*W + w, p, q]      (stride-16 column)
// ---------------------------------------------------------------------------
__global__ __launch_bounds__(256)
void extract_factors(const float* __restrict__ basis,
                     float* __restrict__ Bu,
                     float* __restrict__ Bv) {
    int tid = blockIdx.x * 256 + threadIdx.x;      // 0..16383
    if (tid < Hh * P16) {
        int h = tid >> 4, p = tid & 15;
        const float4* row = (const float4*)(basis + (size_t)h * Ww * (P16 * Q16) + p * Q16);
        float4 a = row[0], b = row[1], c = row[2], d = row[3];   // 64 B
        float s = ((a.x + a.y) + (a.z + a.w)) + ((b.x + b.y) + (b.z + b.w))
                + ((c.x + c.y) + (c.z + c.w)) + ((d.x + d.y) + (d.z + d.w));
        Bu[tid] = s;
    } else {
        int t2 = tid - Hh * P16;
        int w = t2 >> 4, q = t2 & 15;
        const float* col = basis + (size_t)w * (P16 * Q16) + q;
        float s = 0.f;
        #pragma unroll
        for (int p = 0; p < P16; ++p) s += col[p * Q16];
        Bv[t2] = s;
    }
}

// ---------------------------------------------------------------------------
// Kernel 2 (fully register-resident, zero LDS, zero barriers):
//   thread t owns w-pair w0 = 2t (x lane of float2) and w0+1 (y lane),
//   and ALL 32 h rows of its block's tile.
//   Phase A: T[p] = sum_q K[bc,p,q] * Bv[w,q]  -> 16 x float2 = 32 VGPRs.
//   Phase B: for each h: out = sum_p Bu[h,p] * T[p]; Bu/K addresses are
//   block-uniform -> scalar loads. REGULAR stores (R6 A/B: nt-store path
//   measured ~3.8 TB/s vs 7.1 TB/s regular-store fill kernel; spill is gone
//   so write-allocate eviction pressure no longer matters).
// ---------------------------------------------------------------------------
__global__ __launch_bounds__(256, 2)
void bezier_eval(const float* __restrict__ K,
                 const float* __restrict__ Bu,
                 const float* __restrict__ Bv,
                 float* __restrict__ out) {
    const int t     = threadIdx.x;       // 0..255
    const int htile = blockIdx.x;        // 0..15
    const int bc    = blockIdx.y;        // 0..127

    const float* __restrict__ Kp = K + (size_t)bc * (P16 * Q16);  // uniform

    // ---- Phase A: build T[p] = (T[p][2t], T[p][2t+1]) ----
    float2 T[P16];
    #pragma unroll
    for (int p = 0; p < P16; ++p) T[p] = make_float2(0.f, 0.f);

    // Bv rows 2t (128B-aligned per thread) and 2t+1
    const float4* bvv = (const float4*)(Bv + (size_t)(2 * t) * Q16);

    #pragma unroll
    for (int qb = 0; qb < 2; ++qb) {               // q in blocks of 8: bv live = 16 regs
        float4 r00 = bvv[qb * 2 + 0], r01 = bvv[qb * 2 + 1];         // row 2t
        float4 r10 = bvv[4 + qb * 2 + 0], r11 = bvv[4 + qb * 2 + 1]; // row 2t+1
        #pragma unroll
        for (int p = 0; p < P16; ++p) {
            const float* kq = Kp + p * Q16 + qb * 8;   // uniform -> scalar loads
            float2 s = T[p];
            s.x = fmaf(kq[0], r00.x, s.x);  s.y = fmaf(kq[0], r10.x, s.y);
            s.x = fmaf(kq[1], r00.y, s.x);  s.y = fmaf(kq[1], r10.y, s.y);
            s.x = fmaf(kq[2], r00.z, s.x);  s.y = fmaf(kq[2], r10.z, s.y);
            s.x = fmaf(kq[3], r00.w, s.x);  s.y = fmaf(kq[3], r10.w, s.y);
            s.x = fmaf(kq[4], r01.x, s.x);  s.y = fmaf(kq[4], r11.x, s.y);
            s.x = fmaf(kq[5], r01.y, s.x);  s.y = fmaf(kq[5], r11.y, s.y);
            s.x = fmaf(kq[6], r01.z, s.x);  s.y = fmaf(kq[6], r11.z, s.y);
            s.x = fmaf(kq[7], r01.w, s.x);  s.y = fmaf(kq[7], r11.w, s.y);
            T[p] = s;
        }
    }

    // ---- Phase B: 32 output rows, Bu row is block-uniform ----
    const float* __restrict__ bu = Bu + (size_t)htile * (HTILE * P16);
    float* __restrict__ op =
        out + ((size_t)bc * Hh + (size_t)htile * HTILE) * Ww + 2 * t;

    #pragma unroll 4
    for (int h = 0; h < HTILE; ++h) {
        const float* br = bu + h * P16;            // uniform -> scalar loads
        float ax = 0.f, ay = 0.f;
        #pragma unroll
        for (int p = 0; p < P16; ++p) {
            float b = br[p];
            ax = fmaf(b, T[p].x, ax);
            ay = fmaf(b, T[p].y, ay);
        }
        *(float2*)(op + (size_t)h * Ww) = make_float2(ax, ay);   // regular store
    }
}

extern "C" void kernel_launch(void* const* d_in, const int* in_sizes, int n_in,
                              void* d_out, int out_size, void* d_ws, size_t ws_size,
                              hipStream_t stream) {
    const float* K     = (const float*)d_in[0];   // [128, 16, 16]
    const float* basis = (const float*)d_in[1];   // [262144, 16, 16]
    float* out = (float*)d_out;                   // [128, 512, 512]

    float* Bu = (float*)d_ws;                     // [512][16]  (32 KiB)
    float* Bv = Bu + Hh * P16;                    // [512][16]  (32 KiB)

    extract_factors<<<64, 256, 0, stream>>>(basis, Bu, Bv);

    dim3 grid(NHT, BC);                           // 2048 blocks
    bezier_eval<<<grid, 256, 0, stream>>>(K, Bu, Bv, out);
}

// Round 8
// 38.787 us; speedup vs baseline: 5.8068x; 1.0180x over previous
//
#include <hip/hip_runtime.h>
#include <hip/hip_bf16.h>

// Problem constants (from reference): B=8, C=16, H=512, W=512, M=15, N=15
#define BC    128          // B*C
#define Hh    512
#define Ww    512
#define P16   16           // M+1
#define Q16   16           // N+1
#define HTILE 64           // h rows per eval block -> grid 8*128 = 1024 = 4 blocks/CU, ONE round
#define NHT   (Hh / HTILE) // 8 h-tiles

// ---------------------------------------------------------------------------
// Kernel 1: extract separable factors from the provided basis input.
// basis[n, p, q] = Bu[h,p] * Bv[w,q] with n = h*W + w; Bernstein rows sum to 1.
//   Bu[h,p] = sum_q basis[h*W + 0, p, q]      (16 contiguous floats)
//   Bv[w,q] = sum_p basis[0*W + w, p, q]      (stride-16 column)
// ---------------------------------------------------------------------------
__global__ __launch_bounds__(256)
void extract_factors(const float* __restrict__ basis,
                     float* __restrict__ Bu,
                     float* __restrict__ Bv) {
    int tid = blockIdx.x * 256 + threadIdx.x;      // 0..16383
    if (tid < Hh * P16) {
        int h = tid >> 4, p = tid & 15;
        const float4* row = (const float4*)(basis + (size_t)h * Ww * (P16 * Q16) + p * Q16);
        float4 a = row[0], b = row[1], c = row[2], d = row[3];   // 64 B
        float s = ((a.x + a.y) + (a.z + a.w)) + ((b.x + b.y) + (b.z + b.w))
                + ((c.x + c.y) + (c.z + c.w)) + ((d.x + d.y) + (d.z + d.w));
        Bu[tid] = s;
    } else {
        int t2 = tid - Hh * P16;
        int w = t2 >> 4, q = t2 & 15;
        const float* col = basis + (size_t)w * (P16 * Q16) + q;
        float s = 0.f;
        #pragma unroll
        for (int p = 0; p < P16; ++p) s += col[p * Q16];
        Bv[t2] = s;
    }
}

// ---------------------------------------------------------------------------
// Kernel 2 (fully register-resident, zero LDS, zero barriers):
//   thread t owns w-pair w0 = 2t (x of float2) / w0+1 (y), and ALL 64 h rows
//   of its block's tile.
//   Phase A: T[p] = sum_q K[bc,p,q] * Bv[w,q]  -> 16 x float2 = 32 VGPRs.
//   Phase B: for each h: out = sum_p Bu[h,p] * T[p]; Bu/K addresses are
//   block-uniform -> scalar loads.
//   __launch_bounds__(256,4): VGPR cap 128 -> 4 waves/SIMD -> 4 blocks/CU,
//   grid 1024 = exactly one co-resident round (R7 lesson: (256,2) allowed
//   a VGPR allocation that split the 2048-block grid into 2 rounds).
// ---------------------------------------------------------------------------
__global__ __launch_bounds__(256, 4)
void bezier_eval(const float* __restrict__ K,
                 const float* __restrict__ Bu,
                 const float* __restrict__ Bv,
                 float* __restrict__ out) {
    const int t     = threadIdx.x;       // 0..255
    const int htile = blockIdx.x;        // 0..7
    const int bc    = blockIdx.y;        // 0..127

    const float* __restrict__ Kp = K + (size_t)bc * (P16 * Q16);  // uniform

    // ---- Phase A: build T[p] = (T[p][2t], T[p][2t+1]) ----
    float2 T[P16];
    #pragma unroll
    for (int p = 0; p < P16; ++p) T[p] = make_float2(0.f, 0.f);

    // Bv rows 2t (128B-aligned per thread) and 2t+1
    const float4* bvv = (const float4*)(Bv + (size_t)(2 * t) * Q16);

    #pragma unroll
    for (int qb = 0; qb < 2; ++qb) {               // q in blocks of 8: bv live = 16 regs
        float4 r00 = bvv[qb * 2 + 0], r01 = bvv[qb * 2 + 1];         // row 2t
        float4 r10 = bvv[4 + qb * 2 + 0], r11 = bvv[4 + qb * 2 + 1]; // row 2t+1
        #pragma unroll
        for (int p = 0; p < P16; ++p) {
            const float* kq = Kp + p * Q16 + qb * 8;   // uniform -> scalar loads
            float2 s = T[p];
            s.x = fmaf(kq[0], r00.x, s.x);  s.y = fmaf(kq[0], r10.x, s.y);
            s.x = fmaf(kq[1], r00.y, s.x);  s.y = fmaf(kq[1], r10.y, s.y);
            s.x = fmaf(kq[2], r00.z, s.x);  s.y = fmaf(kq[2], r10.z, s.y);
            s.x = fmaf(kq[3], r00.w, s.x);  s.y = fmaf(kq[3], r10.w, s.y);
            s.x = fmaf(kq[4], r01.x, s.x);  s.y = fmaf(kq[4], r11.x, s.y);
            s.x = fmaf(kq[5], r01.y, s.x);  s.y = fmaf(kq[5], r11.y, s.y);
            s.x = fmaf(kq[6], r01.z, s.x);  s.y = fmaf(kq[6], r11.z, s.y);
            s.x = fmaf(kq[7], r01.w, s.x);  s.y = fmaf(kq[7], r11.w, s.y);
            T[p] = s;
        }
    }

    // ---- Phase B: 64 output rows, Bu row is block-uniform ----
    const float* __restrict__ bu = Bu + (size_t)htile * (HTILE * P16);
    float* __restrict__ op =
        out + ((size_t)bc * Hh + (size_t)htile * HTILE) * Ww + 2 * t;

    #pragma unroll 4
    for (int h = 0; h < HTILE; ++h) {
        const float* br = bu + h * P16;            // uniform -> scalar loads
        float ax = 0.f, ay = 0.f;
        #pragma unroll
        for (int p = 0; p < P16; ++p) {
            float b = br[p];
            ax = fmaf(b, T[p].x, ax);
            ay = fmaf(b, T[p].y, ay);
        }
        *(float2*)(op + (size_t)h * Ww) = make_float2(ax, ay);   // regular b64 store
    }
}

extern "C" void kernel_launch(void* const* d_in, const int* in_sizes, int n_in,
                              void* d_out, int out_size, void* d_ws, size_t ws_size,
                              hipStream_t stream) {
    const float* K     = (const float*)d_in[0];   // [128, 16, 16]
    const float* basis = (const float*)d_in[1];   // [262144, 16, 16]
    float* out = (float*)d_out;                   // [128, 512, 512]

    float* Bu = (float*)d_ws;                     // [512][16]  (32 KiB)
    float* Bv = Bu + Hh * P16;                    // [512][16]  (32 KiB)

    extract_factors<<<64, 256, 0, stream>>>(basis, Bu, Bv);

    dim3 grid(NHT, BC);                           // 1024 blocks = 4/CU, one round
    bezier_eval<<<grid, 256, 0, stream>>>(K, Bu, Bv, out);
}

// Round 9
// 35.911 us; speedup vs baseline: 6.2718x; 1.0801x over previous
//
#include <hip/hip_runtime.h>
#include <hip/hip_bf16.h>

// Problem constants (from reference): B=8, C=16, H=512, W=512, M=15, N=15
#define BC    128          // B*C
#define Hh    512
#define Ww    512
#define P16   16           // M+1
#define Q16   16           // N+1
#define HTILE 64           // h rows per eval block -> grid 8*128 = 1024 = 4 blocks/CU
#define NHT   (Hh / HTILE) // 8 h-tiles

// ---------------------------------------------------------------------------
// Kernel 1: extract separable factors from the provided basis input.
//   Bu[h,p] = sum_q basis[h*W + 0, p, q]   (16 contiguous floats, float4 loads)
//   Bv[w,q] = sum_p basis[0*W + w, p, q]   (column sums; float4 q-groups so
//             each load instruction touches 16 cache lines instead of 64)
// 8192 Bu threads + 2048 Bv-float4 threads = 10240 = 40 blocks x 256.
// ---------------------------------------------------------------------------
__global__ __launch_bounds__(256)
void extract_factors(const float* __restrict__ basis,
                     float* __restrict__ Bu,
                     float* __restrict__ Bv) {
    int tid = blockIdx.x * 256 + threadIdx.x;      // 0..10239
    if (tid < Hh * P16) {
        int h = tid >> 4, p = tid & 15;
        const float4* row = (const float4*)(basis + (size_t)h * Ww * (P16 * Q16) + p * Q16);
        float4 a = row[0], b = row[1], c = row[2], d = row[3];   // 64 B
        float s = ((a.x + a.y) + (a.z + a.w)) + ((b.x + b.y) + (b.z + b.w))
                + ((c.x + c.y) + (c.z + c.w)) + ((d.x + d.y) + (d.z + d.w));
        Bu[tid] = s;
    } else {
        int t2 = tid - Hh * P16;                   // 0..2047
        int w = t2 >> 2, qg = t2 & 3;              // q-group of 4
        const float4* base = (const float4*)(basis + (size_t)w * (P16 * Q16)) + qg;
        float4 s = make_float4(0.f, 0.f, 0.f, 0.f);
        #pragma unroll
        for (int p = 0; p < P16; ++p) {
            float4 v = base[p * 4];                // [w, p, qg*4 .. +3], 64B-coalesced x4 lanes
            s.x += v.x; s.y += v.y; s.z += v.z; s.w += v.w;
        }
        *(float4*)&Bv[(size_t)w * Q16 + qg * 4] = s;
    }
}

// ---------------------------------------------------------------------------
// Kernel 2 (register-resident, zero LDS, zero barriers, b128 stores):
//   thread t owns w-pair w0 = 2t; T[p] = sum_q K[bc,p,q]*Bv[w,q] (32 VGPRs).
//   Phase B walks h in PAIRS: compute both rows' float2 results, exchange
//   with adjacent lane via __shfl_xor(.,1); even lanes store row h as one
//   float4 (w=2t..2t+3), odd lanes store row h+1 at w=2t-2..2t+1.
//   -> 16 B/lane stores (fill-kernel-parity), half the store instructions.
// ---------------------------------------------------------------------------
__global__ __launch_bounds__(256, 4)
void bezier_eval(const float* __restrict__ K,
                 const float* __restrict__ Bu,
                 const float* __restrict__ Bv,
                 float* __restrict__ out) {
    const int t     = threadIdx.x;       // 0..255
    const int htile = blockIdx.x;        // 0..7
    const int bc    = blockIdx.y;        // 0..127

    const float* __restrict__ Kp = K + (size_t)bc * (P16 * Q16);  // uniform

    // ---- Phase A: build T[p] = (T[p][2t], T[p][2t+1]) ----
    float2 T[P16];
    #pragma unroll
    for (int p = 0; p < P16; ++p) T[p] = make_float2(0.f, 0.f);

    const float4* bvv = (const float4*)(Bv + (size_t)(2 * t) * Q16);

    #pragma unroll
    for (int qb = 0; qb < 2; ++qb) {               // q in blocks of 8
        float4 r00 = bvv[qb * 2 + 0], r01 = bvv[qb * 2 + 1];         // row 2t
        float4 r10 = bvv[4 + qb * 2 + 0], r11 = bvv[4 + qb * 2 + 1]; // row 2t+1
        #pragma unroll
        for (int p = 0; p < P16; ++p) {
            const float* kq = Kp + p * Q16 + qb * 8;   // uniform -> scalar loads
            float2 s = T[p];
            s.x = fmaf(kq[0], r00.x, s.x);  s.y = fmaf(kq[0], r10.x, s.y);
            s.x = fmaf(kq[1], r00.y, s.x);  s.y = fmaf(kq[1], r10.y, s.y);
            s.x = fmaf(kq[2], r00.z, s.x);  s.y = fmaf(kq[2], r10.z, s.y);
            s.x = fmaf(kq[3], r00.w, s.x);  s.y = fmaf(kq[3], r10.w, s.y);
            s.x = fmaf(kq[4], r01.x, s.x);  s.y = fmaf(kq[4], r11.x, s.y);
            s.x = fmaf(kq[5], r01.y, s.x);  s.y = fmaf(kq[5], r11.y, s.y);
            s.x = fmaf(kq[6], r01.z, s.x);  s.y = fmaf(kq[6], r11.z, s.y);
            s.x = fmaf(kq[7], r01.w, s.x);  s.y = fmaf(kq[7], r11.w, s.y);
            T[p] = s;
        }
    }

    // ---- Phase B: 64 rows in pairs; b128 stores via lane-pair repack ----
    const float* __restrict__ bu = Bu + (size_t)htile * (HTILE * P16);
    // outbase points at this thread's own w0 = 2t in row 0 of the tile.
    float* __restrict__ outbase =
        out + ((size_t)bc * Hh + (size_t)htile * HTILE) * Ww + 2 * t;

    const bool odd = (t & 1);
    // store column offset: even lane stores at its own w0; odd at w0-2.
    const int wofs = odd ? -2 : 0;

    #pragma unroll 4
    for (int h = 0; h < HTILE; h += 2) {
        const float* br0 = bu + h * P16;           // uniform -> scalar loads
        const float* br1 = br0 + P16;
        float ax = 0.f, ay = 0.f, bx = 0.f, by = 0.f;
        #pragma unroll
        for (int p = 0; p < P16; ++p) {
            float c0 = br0[p], c1 = br1[p];
            ax = fmaf(c0, T[p].x, ax);
            ay = fmaf(c0, T[p].y, ay);
            bx = fmaf(c1, T[p].x, bx);
            by = fmaf(c1, T[p].y, by);
        }
        // exchange with adjacent lane (t^1): even lane collects partner's
        // row-h pair; odd lane collects partner's row-(h+1) pair.
        float sx = __shfl_xor(ax, 1);
        float sy = __shfl_xor(ay, 1);
        float ux = __shfl_xor(bx, 1);
        float uy = __shfl_xor(by, 1);
        float4 v = odd ? make_float4(ux, uy, bx, by)    // row h+1, w = 2t-2..2t+1
                       : make_float4(ax, ay, sx, sy);   // row h,   w = 2t..2t+3
        const int hrow = h + (odd ? 1 : 0);
        *(float4*)(outbase + (size_t)hrow * Ww + wofs) = v;  // global_store_dwordx4
    }
}

extern "C" void kernel_launch(void* const* d_in, const int* in_sizes, int n_in,
                              void* d_out, int out_size, void* d_ws, size_t ws_size,
                              hipStream_t stream) {
    const float* K     = (const float*)d_in[0];   // [128, 16, 16]
    const float* basis = (const float*)d_in[1];   // [262144, 16, 16]
    float* out = (float*)d_out;                   // [128, 512, 512]

    float* Bu = (float*)d_ws;                     // [512][16]  (32 KiB)
    float* Bv = Bu + Hh * P16;                    // [512][16]  (32 KiB)

    extract_factors<<<40, 256, 0, stream>>>(basis, Bu, Bv);

    dim3 grid(NHT, BC);                           // 1024 blocks = 4/CU, one round
    bezier_eval<<<grid, 256, 0, stream>>>(K, Bu, Bv, out);
}